// Round 5
// baseline (649.720 us; speedup 1.0000x reference)
//
#include <hip/hip_runtime.h>
#include <math.h>

#define N_NODES 100000
#define N_EDGES 1600000
#define NGR 64
#define IMG_F 50176
#define NCLS 38
#define KSPLIT 49        // 49 K-slabs of 1024 (49*1024 = 50176 exactly)

// bucketed CSR build (no global atomics, no memset)
#define NBUCK 196        // node buckets of 512 nodes
#define NB_BUCK 391      // pass-1 edge blocks (4096 edges each)
#define CELLCAP 64       // per-(bucket,block) cell capacity (Poisson mean ~21)
#define BCAP 9216        // per-bucket csr capacity (mean 8192, +11 sigma)
#define EPB 16           // edges per thread in bucket pass

#define NB_IMG 196       // 4 col-blocks x 49 K-slabs
#define NB_GCN1 1563     // ceil(100000/64)
#define NB_AGG 6250      // 100000/16
#define NB_FRONT (NB_IMG + NB_GCN1 + NB_BUCK)   // 2150

typedef short bf16x8 __attribute__((ext_vector_type(8)));
typedef float f32x4 __attribute__((ext_vector_type(4)));
typedef unsigned int uint;

// fp32 pair -> packed bf16x2 (RNE)
__device__ __forceinline__ uint pk2(float a, float b) {
  uint ua = __float_as_uint(a), ub = __float_as_uint(b);
  ua = (ua + 0x7fffu + ((ua >> 16) & 1u)) >> 16;
  ub = (ub + 0x7fffu + ((ub >> 16) & 1u)) >> 16;
  return ua | (ub << 16);
}
__device__ __forceinline__ unsigned short f2bf(float x) {
  uint u = __float_as_uint(x);
  u = (u + 0x7fffu + ((u >> 16) & 1u)) >> 16;
  return (unsigned short)u;
}
__device__ __forceinline__ float bflo(uint u) { return __uint_as_float(u << 16); }
__device__ __forceinline__ float bfhi(uint u) { return __uint_as_float(u & 0xffff0000u); }

__device__ __forceinline__ int lower_bound_i(const int* __restrict__ a, int n, int v) {
  int lo = 0, hi = n;
  while (lo < hi) { int mid = (lo + hi) >> 1; if (a[mid] < v) lo = mid + 1; else hi = mid; }
  return lo;
}

// ================= role: edge bucketing (pass 1) =================
__device__ __forceinline__ void role_bucket(char* smemc, int blk,
    const int* __restrict__ src, const int* __restrict__ dst,
    uint* __restrict__ ebuf, int* __restrict__ cnt) {
  int* lhist = (int*)smemc;        // 256 ints
  int* lcur  = lhist + 256;        // 256 ints
  const int t = threadIdx.x;
  lhist[t] = 0; lcur[t] = 0;
  __syncthreads();
  const int e0 = blk * (EPB * 256);
  uint p[EPB]; int k[EPB];
#pragma unroll
  for (int j = 0; j < EPB; j++) {
    int e = e0 + j * 256 + t;
    if (e < N_EDGES) {
      int s = src[e], d = dst[e];
      p[j] = (uint)s | ((uint)(d & 511) << 17);
      k[j] = d >> 9;
      atomicAdd(&lhist[k[j]], 1);
    } else k[j] = -1;
  }
  __syncthreads();
#pragma unroll
  for (int j = 0; j < EPB; j++) {
    if (k[j] >= 0) {
      int pos = atomicAdd(&lcur[k[j]], 1);
      if (pos < CELLCAP)
        ebuf[((size_t)k[j] * NB_BUCK + blk) * CELLCAP + pos] = p[j];
    }
  }
  __syncthreads();
  if (t < NBUCK) {
    int c = lhist[t];
    cnt[t * NB_BUCK + blk] = (c > CELLCAP) ? CELLCAP : c;
  }
}

// ================= role: per-bucket CSR fill (pass 2) =================
// 256 threads. Cell-count scan; per-cell coalesced copy (16-lane group per
// cell) into LDS + histogram; node scan -> deg/row_lo/dinv; LDS-cursor scatter.
__device__ __forceinline__ void role_binfill(char* smemc, int b,
    const uint* __restrict__ ebuf, const int* __restrict__ cnt,
    int* __restrict__ deg, int* __restrict__ row_lo,
    float* __restrict__ dinv, int* __restrict__ csr) {
  int* scnt = (int*)smemc;            // 512 (scan space)
  int* soff = scnt + 512;             // 512 (cell excl offsets)
  int* sdeg = soff + 512;             // 512
  int* scur = sdeg + 512;             // 512 (raw counts, later cursors)
  uint* sedge = (uint*)(scur + 512);  // 9216
  const int t = threadIdx.x;
  const int i0 = t, i1 = t + 256;
  int c0 = (i0 < NB_BUCK) ? cnt[b * NB_BUCK + i0] : 0;
  int c1 = (i1 < NB_BUCK) ? cnt[b * NB_BUCK + i1] : 0;
  scnt[i0] = c0; scnt[i1] = c1;
  scur[i0] = c0; scur[i1] = c1;      // raw counts for copy phase
  __syncthreads();
  for (int off = 1; off < 512; off <<= 1) {
    int v0 = (i0 >= off) ? scnt[i0 - off] : 0;
    int v1 = (i1 >= off) ? scnt[i1 - off] : 0;
    __syncthreads();
    scnt[i0] += v0; scnt[i1] += v1;
    __syncthreads();
  }
  soff[i0] = scnt[i0] - c0;
  soff[i1] = scnt[i1] - c1;
  sdeg[i0] = 0; sdeg[i1] = 0;
  __syncthreads();
  // per-cell coalesced copy + histogram (16 groups of 16 lanes)
  const int grp = t >> 4, lane = t & 15;
  for (int c = grp; c < NB_BUCK; c += 16) {
    int off = soff[c], num = scur[c];
    const uint* cb = &ebuf[((size_t)b * NB_BUCK + c) * CELLCAP];
    for (int j = lane; j < num; j += 16) {
      int pos = off + j;
      if (pos < BCAP) {
        uint e = cb[j];
        sedge[pos] = e;
        atomicAdd(&sdeg[e >> 17], 1);
      }
    }
  }
  __syncthreads();
  int total = scnt[511];
  if (total > BCAP) total = BCAP;
  int d0 = sdeg[i0], d1 = sdeg[i1];
  for (int off = 1; off < 512; off <<= 1) {
    int v0 = (i0 >= off) ? sdeg[i0 - off] : 0;
    int v1 = (i1 >= off) ? sdeg[i1 - off] : 0;
    __syncthreads();
    sdeg[i0] += v0; sdeg[i1] += v1;
    __syncthreads();
  }
  int ex0 = sdeg[i0] - d0, ex1 = sdeg[i1] - d1;
  int n0 = b * 512 + i0, n1 = b * 512 + i1;
  if (n0 < N_NODES) { deg[n0] = d0; row_lo[n0] = b * BCAP + ex0; dinv[n0] = rsqrtf((float)d0 + 1.0f); }
  if (n1 < N_NODES) { deg[n1] = d1; row_lo[n1] = b * BCAP + ex1; dinv[n1] = rsqrtf((float)d1 + 1.0f); }
  scur[i0] = ex0; scur[i1] = ex1;
  __syncthreads();
  for (int j = t; j < total; j += 256) {
    uint e = sedge[j];
    int pos = atomicAdd(&scur[e >> 17], 1);
    csr[(size_t)b * BCAP + pos] = (int)(e & 0x1FFFFu);
  }
}

// ================= role: img GEMM (bf16 MFMA split-K, Bl-only LDS) =================
__device__ __forceinline__ void role_img(char* smemc, int b,
    const float* __restrict__ A, const float* __restrict__ B,
    float* __restrict__ partial) {
  short* Bl = (short*)smemc;           // 32 KB (64 k x 256 cols)
  const int tid = threadIdx.x;
  const int l = tid & 63, w = tid >> 6;
  const int col0 = (b & 3) * 256;
  const int kbase = (b >> 2) * 1024;
  const int kq_l = l >> 4, rr_l = l & 15;
  f32x4 acc[16];
#pragma unroll
  for (int ct = 0; ct < 16; ct++) acc[ct] = (f32x4)(0.f);

  for (int st = 0; st < 16; st++) {
    int k0 = kbase + st * 64;
    // A-fragments direct from global (issued before staging to hide latency)
    bf16x8 af[2];
#pragma unroll
    for (int kst = 0; kst < 2; kst++) {
      const float* ap = &A[(size_t)(w * 16 + rr_l) * IMG_F + k0 + (kst * 4 + kq_l) * 8];
      float4 f0 = *(const float4*)ap;
      float4 f1 = *(const float4*)(ap + 4);
      uint au[4] = {pk2(f0.x, f0.y), pk2(f0.z, f0.w), pk2(f1.x, f1.y), pk2(f1.z, f1.w)};
      af[kst] = *(bf16x8*)au;
    }
    __syncthreads();
    {
      int col4 = tid & 63, koB = tid >> 6;
#pragma unroll
      for (int itb = 0; itb < 2; itb++) {
        int ko = koB + itb * 4;
        const float* bp = &B[(size_t)(k0 + ko * 8) * 1024 + col0 + col4 * 4];
        float fb[8][4];
#pragma unroll
        for (int i2 = 0; i2 < 8; i2++)
          *(float4*)&fb[i2][0] = *(const float4*)(bp + (size_t)i2 * 1024);
        int kst = ko >> 2, kq = ko & 3;
#pragma unroll
        for (int c2 = 0; c2 < 4; c2++) {
          int col = col4 * 4 + c2;
          int ct = col >> 4, colin = col & 15;
          int ci = ((kst * 4 + kq) * 16 + (ct ^ kq)) * 16 + colin;
          uint4 u = make_uint4(pk2(fb[0][c2], fb[1][c2]), pk2(fb[2][c2], fb[3][c2]),
                               pk2(fb[4][c2], fb[5][c2]), pk2(fb[6][c2], fb[7][c2]));
          *(uint4*)&Bl[ci * 8] = u;
        }
      }
    }
    __syncthreads();
#pragma unroll
    for (int kst = 0; kst < 2; kst++) {
#pragma unroll
      for (int ct = 0; ct < 16; ct++) {
        bf16x8 bf = *(bf16x8*)&Bl[(((kst * 4 + kq_l) * 16 + (ct ^ kq_l)) * 16 + rr_l) * 8];
        acc[ct] = __builtin_amdgcn_mfma_f32_16x16x32_bf16(af[kst], bf, acc[ct], 0, 0, 0);
      }
    }
  }
  float* P = partial + (size_t)(b >> 2) * 65536;
#pragma unroll
  for (int ct = 0; ct < 16; ct++)
#pragma unroll
    for (int rg = 0; rg < 4; rg++) {
      int row = w * 16 + (l >> 4) * 4 + rg;
      int col = col0 + ct * 16 + (l & 15);
      P[row * 1024 + col] = acc[ct][rg];
    }
}

// ================= role: node GEMM (Wl-only LDS, A direct from global) ===========
// C[M,N] = scale(row) * (act(A[M,128]) @ W[128,N]) in bf16.
template<int N, bool RELU_BIAS, bool BF16_IN, bool SCALE>
__device__ __forceinline__ void role_gcn(char* smemc, int row0,
    const void* __restrict__ Ain, const float* __restrict__ W,
    const float* __restrict__ abias, const float* __restrict__ dinv,
    unsigned short* __restrict__ C, int M) {
  constexpr int NT16 = N / 16;
  short* Wl = (short*)smemc;            // 256*NT16*8 shorts
  const int tid = threadIdx.x;
  const int l = tid & 63, w = tid >> 6;
  const int kq_l = l >> 4, rr_l = l & 15;

#pragma unroll
  for (int it = 0; it < (N == 128 ? 2 : 1); it++) {
    int mt = tid + it * 256;
    int col4 = mt % (N / 4), ko = mt / (N / 4);
    float fb[8][4];
#pragma unroll
    for (int i2 = 0; i2 < 8; i2++)
      *(float4*)&fb[i2][0] = *(const float4*)&W[(size_t)(ko * 8 + i2) * N + col4 * 4];
    int kst = ko >> 2, kq = ko & 3;
#pragma unroll
    for (int c2 = 0; c2 < 4; c2++) {
      int col = col4 * 4 + c2;
      int ct = col >> 4, colin = col & 15;
      int ci = ((kst * 4 + kq) * NT16 + (ct ^ kq)) * 16 + colin;
      uint4 u = make_uint4(pk2(fb[0][c2], fb[1][c2]), pk2(fb[2][c2], fb[3][c2]),
                           pk2(fb[4][c2], fb[5][c2]), pk2(fb[6][c2], fb[7][c2]));
      *(uint4*)&Wl[ci * 8] = u;
    }
  }

  // A-fragments direct from global: row = row0 + w*16 + rr_l, k-chunk (kst*4+kq_l)*8
  const int row = row0 + w * 16 + rr_l;
  const bool valid = row < M;
  bf16x8 af[4];
#pragma unroll
  for (int kst = 0; kst < 4; kst++) {
    int ko = kst * 4 + kq_l;
    float f[8] = {0.f, 0.f, 0.f, 0.f, 0.f, 0.f, 0.f, 0.f};
    if (valid) {
      if constexpr (BF16_IN) {
        uint4 u = *(const uint4*)((const uint*)Ain + (size_t)row * 64 + ko * 4);
        f[0] = bflo(u.x); f[1] = bfhi(u.x); f[2] = bflo(u.y); f[3] = bfhi(u.y);
        f[4] = bflo(u.z); f[5] = bfhi(u.z); f[6] = bflo(u.w); f[7] = bfhi(u.w);
      } else {
        const float* ap = (const float*)Ain + (size_t)row * 128 + ko * 8;
        *(float4*)&f[0] = *(const float4*)ap;
        *(float4*)&f[4] = *(const float4*)(ap + 4);
      }
      if (RELU_BIAS) {
        const float* bp = &abias[ko * 8];
        float bb[8];
        *(float4*)&bb[0] = *(const float4*)bp;
        *(float4*)&bb[4] = *(const float4*)(bp + 4);
#pragma unroll
        for (int j = 0; j < 8; j++) f[j] = fmaxf(f[j] + bb[j], 0.f);
      }
    }
    uint au[4] = {pk2(f[0], f[1]), pk2(f[2], f[3]), pk2(f[4], f[5]), pk2(f[6], f[7])};
    af[kst] = *(bf16x8*)au;
  }
  __syncthreads();

  f32x4 acc[NT16];
#pragma unroll
  for (int ct = 0; ct < NT16; ct++) acc[ct] = (f32x4)(0.f);
#pragma unroll
  for (int kst = 0; kst < 4; kst++) {
#pragma unroll
    for (int ct = 0; ct < NT16; ct++) {
      bf16x8 bf = *(bf16x8*)&Wl[(((kst * 4 + kq_l) * NT16 + (ct ^ kq_l)) * 16 + rr_l) * 8];
      acc[ct] = __builtin_amdgcn_mfma_f32_16x16x32_bf16(af[kst], bf, acc[ct], 0, 0, 0);
    }
  }
#pragma unroll
  for (int rg = 0; rg < 4; rg++) {
    int orow = row0 + w * 16 + (l >> 4) * 4 + rg;
    if (orow < M) {
      float dsc = SCALE ? dinv[orow] : 1.f;
#pragma unroll
      for (int ct = 0; ct < NT16; ct++)
        C[(size_t)orow * N + ct * 16 + (l & 15)] = f2bf(acc[ct][rg] * dsc);
    }
  }
}

// ================= role: GCN aggregation (gather, bf16, unroll-8) =================
template<int F, int VEC, bool SRCS>
__device__ __forceinline__ void role_agg(int nb,
    const unsigned short* __restrict__ h, const float* __restrict__ dinv,
    const int* __restrict__ row_lo, const int* __restrict__ deg,
    const int* __restrict__ csr_src, unsigned short* __restrict__ out) {
  constexpr int L = F / VEC;    // 16
  constexpr int NPB = 256 / L;  // 16
  constexpr int NU = VEC / 2;
  int n = nb * NPB + threadIdx.x / L;
  int lane = threadIdx.x % L;
  if (n >= N_NODES) return;
  const uint* hu = (const uint*)h;
  const int rs = F / 2;
  float dn = dinv[n];
  float acc[VEC];
  uint r0[NU];
  if constexpr (VEC == 8) *(uint4*)r0 = *(const uint4*)&hu[(size_t)n * rs + lane * NU];
  else                    *(uint2*)r0 = *(const uint2*)&hu[(size_t)n * rs + lane * NU];
#pragma unroll
  for (int j = 0; j < NU; j++) {
    float sw = SRCS ? dn : 1.f;
    acc[2*j] = sw * bflo(r0[j]); acc[2*j+1] = sw * bfhi(r0[j]);
  }
  int lo = row_lo[n], hi = lo + deg[n];
  int i = lo;
  for (; i + 8 <= hi; i += 8) {
    int ss[8];
#pragma unroll
    for (int u = 0; u < 8; u++) ss[u] = csr_src[i + u];
    uint a[8][NU];
#pragma unroll
    for (int u = 0; u < 8; u++) {
      if constexpr (VEC == 8) *(uint4*)a[u] = *(const uint4*)&hu[(size_t)ss[u] * rs + lane * NU];
      else                    *(uint2*)a[u] = *(const uint2*)&hu[(size_t)ss[u] * rs + lane * NU];
    }
    if constexpr (SRCS) {
      float wv[8];
#pragma unroll
      for (int u = 0; u < 8; u++) wv[u] = dinv[ss[u]];
#pragma unroll
      for (int u = 0; u < 8; u++)
#pragma unroll
        for (int j = 0; j < NU; j++) {
          acc[2*j]   = fmaf(wv[u], bflo(a[u][j]), acc[2*j]);
          acc[2*j+1] = fmaf(wv[u], bfhi(a[u][j]), acc[2*j+1]);
        }
    } else {
#pragma unroll
      for (int u = 0; u < 8; u++)
#pragma unroll
        for (int j = 0; j < NU; j++) {
          acc[2*j]   += bflo(a[u][j]);
          acc[2*j+1] += bfhi(a[u][j]);
        }
    }
  }
  for (; i + 2 <= hi; i += 2) {
    int s0 = csr_src[i], s1 = csr_src[i + 1];
    uint a0[NU], a1[NU];
    if constexpr (VEC == 8) {
      *(uint4*)a0 = *(const uint4*)&hu[(size_t)s0 * rs + lane * NU];
      *(uint4*)a1 = *(const uint4*)&hu[(size_t)s1 * rs + lane * NU];
    } else {
      *(uint2*)a0 = *(const uint2*)&hu[(size_t)s0 * rs + lane * NU];
      *(uint2*)a1 = *(const uint2*)&hu[(size_t)s1 * rs + lane * NU];
    }
    float w0 = SRCS ? dinv[s0] : 1.f, w1 = SRCS ? dinv[s1] : 1.f;
#pragma unroll
    for (int j = 0; j < NU; j++) {
      acc[2*j]   = fmaf(w0, bflo(a0[j]), fmaf(w1, bflo(a1[j]), acc[2*j]));
      acc[2*j+1] = fmaf(w0, bfhi(a0[j]), fmaf(w1, bfhi(a1[j]), acc[2*j+1]));
    }
  }
  if (i < hi) {
    int s0 = csr_src[i];
    uint a0[NU];
    if constexpr (VEC == 8) *(uint4*)a0 = *(const uint4*)&hu[(size_t)s0 * rs + lane * NU];
    else                    *(uint2*)a0 = *(const uint2*)&hu[(size_t)s0 * rs + lane * NU];
    float w0 = SRCS ? dinv[s0] : 1.f;
#pragma unroll
    for (int j = 0; j < NU; j++) {
      acc[2*j]   = fmaf(w0, bflo(a0[j]), acc[2*j]);
      acc[2*j+1] = fmaf(w0, bfhi(a0[j]), acc[2*j+1]);
    }
  }
  uint o[NU];
#pragma unroll
  for (int j = 0; j < NU; j++) o[j] = pk2(dn * acc[2*j], dn * acc[2*j+1]);
  uint* op = (uint*)out + (size_t)n * rs + lane * NU;
  if constexpr (VEC == 8) *(uint4*)op = *(uint4*)o;
  else                    *(uint2*)op = *(uint2*)o;
}

// ================= fused kernels =================
__global__ __launch_bounds__(256)
void k_front(const float* __restrict__ img, const float* __restrict__ Wm0,
             float* __restrict__ partial,
             const float* __restrict__ x, const float* __restrict__ W1,
             unsigned short* __restrict__ bufA,
             const int* __restrict__ src, const int* __restrict__ dst,
             uint* __restrict__ ebuf, int* __restrict__ cnt) {
  __shared__ __align__(16) char smem[32768];
  // bijective interleave of roles across hardware block ids (997 coprime to 2150)
  int vb = (int)(((long long)blockIdx.x * 997) % NB_FRONT);
  if (vb < NB_IMG) {
    role_img(smem, vb, img, Wm0, partial);
  } else if (vb < NB_IMG + NB_GCN1) {
    role_gcn<128, false, false, false>(smem, (vb - NB_IMG) * 64, x, W1, nullptr,
                                       nullptr, bufA, N_NODES);
  } else {
    role_bucket(smem, vb - NB_IMG - NB_GCN1, src, dst, ebuf, cnt);
  }
}

__global__ __launch_bounds__(256)
void k_mid(const uint* __restrict__ ebuf, const int* __restrict__ cnt,
           int* __restrict__ deg, int* __restrict__ row_lo,
           float* __restrict__ dinv, int* __restrict__ csr,
           const float* __restrict__ partial, const float* __restrict__ bm0,
           float* __restrict__ tmp1) {
  __shared__ __align__(16) char smem[45056];
  int b = blockIdx.x;
  if (b < NBUCK) {
    role_binfill(smem, b, ebuf, cnt, deg, row_lo, dinv, csr);
  } else {
    int i = (b - NBUCK) * 256 + threadIdx.x;
    float s = bm0[i & 1023];
    for (int ks = 0; ks < KSPLIT; ks++) s += partial[(size_t)ks * 65536 + i];
    tmp1[i] = s;
  }
}

__global__ __launch_bounds__(256)
void k_aggA(const unsigned short* __restrict__ h, const float* __restrict__ dinv,
            const int* __restrict__ row_lo, const int* __restrict__ deg,
            const int* __restrict__ csr, unsigned short* __restrict__ outp,
            const float* __restrict__ T, const float* __restrict__ Wm1,
            const float* __restrict__ bm1, float* __restrict__ x0) {
  __shared__ float red[4][64];
  int b = blockIdx.x;
  if (b < 64) {  // img_gemm2: x0 = T @ Wm1 + bm1
    int r = b;
    int c = threadIdx.x & 63;
    int q = threadIdx.x >> 6;
    float acc = 0.f;
#pragma unroll 8
    for (int k = q; k < 1024; k += 4)
      acc = fmaf(T[r * 1024 + k], Wm1[k * 64 + c], acc);
    red[q][c] = acc;
    __syncthreads();
    if (q == 0) x0[r * 64 + c] = red[0][c] + red[1][c] + red[2][c] + red[3][c] + bm1[c];
  } else {
    role_agg<128, 8, true>(b - 64, h, dinv, row_lo, deg, csr, outp);
  }
}

__global__ __launch_bounds__(256)
void k_gcn2(const unsigned short* __restrict__ Ain, const float* __restrict__ W,
            const float* __restrict__ abias, const float* __restrict__ dinv,
            unsigned short* __restrict__ C) {
  __shared__ __align__(16) char smem[16384];
  role_gcn<64, true, true, true>(smem, blockIdx.x * 64, Ain, W, abias, dinv, C, N_NODES);
}

__global__ __launch_bounds__(256)
void k_agg2(const unsigned short* __restrict__ h, const float* __restrict__ dinv,
            const int* __restrict__ row_lo, const int* __restrict__ deg,
            const int* __restrict__ csr, unsigned short* __restrict__ outp) {
  role_agg<64, 4, false>(blockIdx.x, h, dinv, row_lo, deg, csr, outp);
}

// pool + head, one block per graph (g stays in LDS)
__global__ __launch_bounds__(256)
void k_tail(const unsigned short* __restrict__ h2, const float* __restrict__ b2,
            const int* __restrict__ batch, const float* __restrict__ x0,
            const float* __restrict__ Wmx, const float* __restrict__ bmx,
            const float* __restrict__ Wfc, const float* __restrict__ bfc,
            float* __restrict__ out) {
  int b = blockIdx.x;
  int f = threadIdx.x & 63;
  int q = threadIdx.x >> 6;
  __shared__ float red[4][64];
  __shared__ float sx[128];
  __shared__ float slog[NCLS];
  __shared__ float sred;
  int lo = lower_bound_i(batch, N_NODES, b);
  int hi = lower_bound_i(batch, N_NODES, b + 1);
  float bias = b2[f];
  float acc = 0.f;
  for (int i = lo + q; i < hi; i += 4)
    acc += fmaxf(__uint_as_float((uint)h2[(size_t)i * 64 + f] << 16) + bias, 0.f);
  red[q][f] = acc;
  __syncthreads();
  if (q == 0) red[0][f] = red[0][f] + red[1][f] + red[2][f] + red[3][f];  // g vector
  __syncthreads();
  int c = threadIdx.x;
  if (c < 64) {
    float a2 = bmx[c];
#pragma unroll 8
    for (int k = 0; k < 64; k++) a2 = fmaf(red[0][k], Wmx[k * 64 + c], a2);
    sx[64 + c] = a2;
    sx[c] = x0[b * 64 + c];
  }
  __syncthreads();
  float lg = 0.f;
  if (c < NCLS) {
    lg = bfc[c];
#pragma unroll 8
    for (int k = 0; k < 128; k++) lg = fmaf(sx[k], Wfc[k * NCLS + c], lg);
    slog[c] = lg;
  }
  __syncthreads();
  if (c == 0) {
    float m = -1e30f;
    for (int j = 0; j < NCLS; j++) m = fmaxf(m, slog[j]);
    float s = 0.f;
    for (int j = 0; j < NCLS; j++) s += expf(slog[j] - m);
    sred = m + logf(s);
  }
  __syncthreads();
  if (c < NCLS) out[b * NCLS + c] = lg - sred;
}

// ---------------- launch ----------------
extern "C" void kernel_launch(void* const* d_in, const int* in_sizes, int n_in,
                              void* d_out, int out_size, void* d_ws, size_t ws_size,
                              hipStream_t stream) {
  const float* x    = (const float*)d_in[0];
  const int*   edge = (const int*)d_in[1];
  const float* img  = (const float*)d_in[2];
  const int*   batch= (const int*)d_in[3];
  const float* W1   = (const float*)d_in[4];
  const float* b1   = (const float*)d_in[5];
  const float* W2   = (const float*)d_in[6];
  const float* b2   = (const float*)d_in[7];
  const float* Wm0  = (const float*)d_in[8];
  const float* bm0  = (const float*)d_in[9];
  const float* Wm1  = (const float*)d_in[10];
  const float* bm1  = (const float*)d_in[11];
  const float* Wmx  = (const float*)d_in[12];
  const float* bmx  = (const float*)d_in[13];
  const float* Wfc  = (const float*)d_in[14];
  const float* bfc  = (const float*)d_in[15];
  float* out = (float*)d_out;
  const int* srcp = edge;
  const int* dstp = edge + N_EDGES;

  char* ws = (char*)d_ws;
  size_t off = 0;
  auto alloc = [&](size_t bytes) {
    void* p = ws + off;
    off += (bytes + 255) & ~(size_t)255;
    return p;
  };
  int*   cnt    = (int*)  alloc((size_t)NBUCK * NB_BUCK * 4);
  uint*  ebuf   = (uint*) alloc((size_t)NBUCK * NB_BUCK * CELLCAP * 4);
  int*   csr    = (int*)  alloc((size_t)NBUCK * BCAP * 4);
  int*   deg    = (int*)  alloc((size_t)N_NODES * 4);
  int*   row_lo = (int*)  alloc((size_t)N_NODES * 4);
  float* dinv   = (float*)alloc((size_t)N_NODES * 4);
  unsigned short* bufA = (unsigned short*)alloc((size_t)N_NODES * 128 * 2);
  unsigned short* bufB = (unsigned short*)alloc((size_t)N_NODES * 128 * 2);  // >= partial 12.85 MB
  float* tmp1   = (float*)alloc(64 * 1024 * 4);
  float* x0     = (float*)alloc(64 * 64 * 4);
  float* partial = (float*)bufB;  // used only before agg1 writes bufB (stream-ordered)
  (void)ws_size; (void)in_sizes; (void)n_in; (void)out_size;

  // K1: img GEMM || gcn layer-1 GEMM (unscaled) || edge bucketing (interleaved)
  k_front<<<NB_FRONT, 256, 0, stream>>>(
      img, Wm0, partial, x, W1, bufA, srcp, dstp, ebuf, cnt);
  // K2: per-bucket CSR fill (deg/row_lo/dinv) || img split-K reduce
  k_mid<<<NBUCK + 256, 256, 0, stream>>>(
      ebuf, cnt, deg, row_lo, dinv, csr, partial, bm0, tmp1);
  // K3: img gemm2 || gather-agg layer 1 (applies dinv on both sides)
  k_aggA<<<64 + NB_AGG, 256, 0, stream>>>(
      bufA, dinv, row_lo, deg, csr, bufB, tmp1, Wm1, bm1, x0);
  // K4: gcn layer-2 GEMM (relu+bias, pre-scaled by dinv)
  k_gcn2<<<NB_GCN1, 256, 0, stream>>>(bufB, W2, b1, dinv, bufA);
  // K5: gather-agg layer 2
  k_agg2<<<NB_AGG, 256, 0, stream>>>(bufA, dinv, row_lo, deg, csr, bufB);
  // K6: pool + head
  k_tail<<<NGR, 256, 0, stream>>>(bufB, b2, batch, x0, Wmx, bmx, Wfc, bfc, out);
}

// Round 6
// 528.414 us; speedup vs baseline: 1.2296x; 1.2296x over previous
//
#include <hip/hip_runtime.h>
#include <math.h>

#define N_NODES 100000
#define N_EDGES 1600000
#define NGR 64
#define IMG_F 50176
#define NCLS 38
#define KSPLIT 49        // 49 K-slabs of 1024 (49*1024 = 50176 exactly)

// bucketed CSR build (no global atomics, no memset)
#define NBUCK 196        // node buckets of 512 nodes
#define NB_BUCK 391      // pass-1 edge blocks (4096 edges each)
#define CELLCAP 64       // per-(bucket,block) cell capacity (Poisson mean ~21)
#define BCAP 9216        // per-bucket csr capacity (mean 8192, +11 sigma)
#define EPB 16           // edges per thread in bucket pass

#define NB_IMG 196       // 4 col-blocks x 49 K-slabs
#define NB_GCN1 1563     // ceil(100000/64)
#define NB_AGGP 6250     // 100000/16
#define NB_FRONT (NB_IMG + NB_GCN1 + NB_BUCK)   // 2150

typedef short bf16x8 __attribute__((ext_vector_type(8)));
typedef float f32x4 __attribute__((ext_vector_type(4)));
typedef unsigned int uint;

// fp32 pair -> packed bf16x2 (RNE)
__device__ __forceinline__ uint pk2(float a, float b) {
  uint ua = __float_as_uint(a), ub = __float_as_uint(b);
  ua = (ua + 0x7fffu + ((ua >> 16) & 1u)) >> 16;
  ub = (ub + 0x7fffu + ((ub >> 16) & 1u)) >> 16;
  return ua | (ub << 16);
}
__device__ __forceinline__ unsigned short f2bf(float x) {
  uint u = __float_as_uint(x);
  u = (u + 0x7fffu + ((u >> 16) & 1u)) >> 16;
  return (unsigned short)u;
}
__device__ __forceinline__ float bflo(uint u) { return __uint_as_float(u << 16); }
__device__ __forceinline__ float bfhi(uint u) { return __uint_as_float(u & 0xffff0000u); }

// ================= role: edge bucketing (pass 1) =================
__device__ __forceinline__ void role_bucket(char* smemc, int blk,
    const int* __restrict__ src, const int* __restrict__ dst,
    uint* __restrict__ ebuf, int* __restrict__ cnt) {
  int* lhist = (int*)smemc;        // 256 ints
  int* lcur  = lhist + 256;        // 256 ints
  const int t = threadIdx.x;
  lhist[t] = 0; lcur[t] = 0;
  __syncthreads();
  const int e0 = blk * (EPB * 256);
  uint p[EPB]; int k[EPB];
#pragma unroll
  for (int j = 0; j < EPB; j++) {
    int e = e0 + j * 256 + t;
    if (e < N_EDGES) {
      int s = src[e], d = dst[e];
      p[j] = (uint)s | ((uint)(d & 511) << 17);
      k[j] = d >> 9;
      atomicAdd(&lhist[k[j]], 1);
    } else k[j] = -1;
  }
  __syncthreads();
#pragma unroll
  for (int j = 0; j < EPB; j++) {
    if (k[j] >= 0) {
      int pos = atomicAdd(&lcur[k[j]], 1);
      if (pos < CELLCAP)
        ebuf[((size_t)k[j] * NB_BUCK + blk) * CELLCAP + pos] = p[j];
    }
  }
  __syncthreads();
  if (t < NBUCK) {
    int c = lhist[t];
    cnt[t * NB_BUCK + blk] = (c > CELLCAP) ? CELLCAP : c;
  }
}

// ================= role: per-bucket CSR fill (pass 2) =================
__device__ __forceinline__ void role_binfill(char* smemc, int b,
    const uint* __restrict__ ebuf, const int* __restrict__ cnt,
    int* __restrict__ deg, int* __restrict__ row_lo,
    float* __restrict__ dinv, int* __restrict__ csr) {
  int* scnt = (int*)smemc;            // 512 (scan space)
  int* soff = scnt + 512;             // 512 (cell excl offsets)
  int* sdeg = soff + 512;             // 512
  int* scur = sdeg + 512;             // 512 (raw counts, later cursors)
  uint* sedge = (uint*)(scur + 512);  // 9216
  const int t = threadIdx.x;
  const int i0 = t, i1 = t + 256;
  int c0 = (i0 < NB_BUCK) ? cnt[b * NB_BUCK + i0] : 0;
  int c1 = (i1 < NB_BUCK) ? cnt[b * NB_BUCK + i1] : 0;
  scnt[i0] = c0; scnt[i1] = c1;
  scur[i0] = c0; scur[i1] = c1;
  __syncthreads();
  for (int off = 1; off < 512; off <<= 1) {
    int v0 = (i0 >= off) ? scnt[i0 - off] : 0;
    int v1 = (i1 >= off) ? scnt[i1 - off] : 0;
    __syncthreads();
    scnt[i0] += v0; scnt[i1] += v1;
    __syncthreads();
  }
  soff[i0] = scnt[i0] - c0;
  soff[i1] = scnt[i1] - c1;
  sdeg[i0] = 0; sdeg[i1] = 0;
  __syncthreads();
  // per-cell coalesced copy + histogram (16 groups of 16 lanes)
  const int grp = t >> 4, lane = t & 15;
  for (int c = grp; c < NB_BUCK; c += 16) {
    int off = soff[c], num = scur[c];
    const uint* cb = &ebuf[((size_t)b * NB_BUCK + c) * CELLCAP];
    for (int j = lane; j < num; j += 16) {
      int pos = off + j;
      if (pos < BCAP) {
        uint e = cb[j];
        sedge[pos] = e;
        atomicAdd(&sdeg[e >> 17], 1);
      }
    }
  }
  __syncthreads();
  int total = scnt[511];
  if (total > BCAP) total = BCAP;
  int d0 = sdeg[i0], d1 = sdeg[i1];
  for (int off = 1; off < 512; off <<= 1) {
    int v0 = (i0 >= off) ? sdeg[i0 - off] : 0;
    int v1 = (i1 >= off) ? sdeg[i1 - off] : 0;
    __syncthreads();
    sdeg[i0] += v0; sdeg[i1] += v1;
    __syncthreads();
  }
  int ex0 = sdeg[i0] - d0, ex1 = sdeg[i1] - d1;
  int n0 = b * 512 + i0, n1 = b * 512 + i1;
  if (n0 < N_NODES) { deg[n0] = d0; row_lo[n0] = b * BCAP + ex0; dinv[n0] = rsqrtf((float)d0 + 1.0f); }
  if (n1 < N_NODES) { deg[n1] = d1; row_lo[n1] = b * BCAP + ex1; dinv[n1] = rsqrtf((float)d1 + 1.0f); }
  scur[i0] = ex0; scur[i1] = ex1;
  __syncthreads();
  for (int j = t; j < total; j += 256) {
    uint e = sedge[j];
    int pos = atomicAdd(&scur[e >> 17], 1);
    csr[(size_t)b * BCAP + pos] = (int)(e & 0x1FFFFu);
  }
}

// ================= role: img GEMM (round-4 form: Al+Bl staged) =================
__device__ __forceinline__ void role_img(char* smemc, int b,
    const float* __restrict__ A, const float* __restrict__ B,
    float* __restrict__ partial) {
  short* Al = (short*)smemc;           // 8 KB  (64 rows x 64 k)
  short* Bl = (short*)(smemc + 8192);  // 32 KB (64 k x 256 cols)
  const int tid = threadIdx.x;
  const int l = tid & 63, w = tid >> 6;
  const int col0 = (b & 3) * 256;
  const int kbase = (b >> 2) * 1024;
  const int kq_l = l >> 4, rr_l = l & 15;
  f32x4 acc[16];
#pragma unroll
  for (int ct = 0; ct < 16; ct++) acc[ct] = (f32x4)(0.f);

  for (int st = 0; st < 16; st++) {
    int k0 = kbase + st * 64;
    __syncthreads();
#pragma unroll
    for (int it = 0; it < 2; it++) {
      int c = tid + it * 256;
      int r = c >> 3, ko = c & 7;
      const float* ap = &A[(size_t)r * IMG_F + k0 + ko * 8];
      float4 f0 = *(const float4*)ap;
      float4 f1 = *(const float4*)(ap + 4);
      int kst = ko >> 2, kq = ko & 3, rt = r >> 4, rr = r & 15;
      int ci = ((kst * 4 + kq) * 4 + (rt ^ kq)) * 16 + rr;
      uint4 u = make_uint4(pk2(f0.x, f0.y), pk2(f0.z, f0.w),
                           pk2(f1.x, f1.y), pk2(f1.z, f1.w));
      *(uint4*)&Al[ci * 8] = u;
    }
    {
      int col4 = tid & 63, koB = tid >> 6;
#pragma unroll
      for (int itb = 0; itb < 2; itb++) {
        int ko = koB + itb * 4;
        const float* bp = &B[(size_t)(k0 + ko * 8) * 1024 + col0 + col4 * 4];
        float fb[8][4];
#pragma unroll
        for (int i2 = 0; i2 < 8; i2++)
          *(float4*)&fb[i2][0] = *(const float4*)(bp + (size_t)i2 * 1024);
        int kst = ko >> 2, kq = ko & 3;
#pragma unroll
        for (int c2 = 0; c2 < 4; c2++) {
          int col = col4 * 4 + c2;
          int ct = col >> 4, colin = col & 15;
          int ci = ((kst * 4 + kq) * 16 + (ct ^ kq)) * 16 + colin;
          uint4 u = make_uint4(pk2(fb[0][c2], fb[1][c2]), pk2(fb[2][c2], fb[3][c2]),
                               pk2(fb[4][c2], fb[5][c2]), pk2(fb[6][c2], fb[7][c2]));
          *(uint4*)&Bl[ci * 8] = u;
        }
      }
    }
    __syncthreads();
#pragma unroll
    for (int kst = 0; kst < 2; kst++) {
      bf16x8 af = *(bf16x8*)&Al[(((kst * 4 + kq_l) * 4 + (w ^ kq_l)) * 16 + rr_l) * 8];
#pragma unroll
      for (int ct = 0; ct < 16; ct++) {
        bf16x8 bf = *(bf16x8*)&Bl[(((kst * 4 + kq_l) * 16 + (ct ^ kq_l)) * 16 + rr_l) * 8];
        acc[ct] = __builtin_amdgcn_mfma_f32_16x16x32_bf16(af, bf, acc[ct], 0, 0, 0);
      }
    }
  }
  float* P = partial + (size_t)(b >> 2) * 65536;
#pragma unroll
  for (int ct = 0; ct < 16; ct++)
#pragma unroll
    for (int rg = 0; rg < 4; rg++) {
      int row = w * 16 + (l >> 4) * 4 + rg;
      int col = col0 + ct * 16 + (l & 15);
      P[row * 1024 + col] = acc[ct][rg];
    }
}

// ================= role: gcn layer-1 GEMM (round-4 form: Al+Wl staged) ==========
__device__ __forceinline__ void role_gcn1(char* smemc, int row0,
    const float* __restrict__ Ain, const float* __restrict__ W,
    unsigned short* __restrict__ C) {
  constexpr int NT16 = 8;  // N = 128
  short* Al = (short*)smemc;            // 16 KB
  short* Wl = (short*)(smemc + 16384);  // 32 KB
  const int tid = threadIdx.x;
  const int l = tid & 63, w = tid >> 6;
  const int kq_l = l >> 4, rr_l = l & 15;

#pragma unroll
  for (int it = 0; it < 4; it++) {
    int c = tid + it * 256;
    int r = c >> 4, ko = c & 15;
    int row = row0 + r;
    float f[8] = {0.f, 0.f, 0.f, 0.f, 0.f, 0.f, 0.f, 0.f};
    if (row < N_NODES) {
      const float* ap = Ain + (size_t)row * 128 + ko * 8;
      *(float4*)&f[0] = *(const float4*)ap;
      *(float4*)&f[4] = *(const float4*)(ap + 4);
    }
    int kst = ko >> 2, kq = ko & 3, rt = r >> 4, rr = r & 15;
    int ci = ((kst * 4 + kq) * 4 + (rt ^ kq)) * 16 + rr;
    uint4 u = make_uint4(pk2(f[0], f[1]), pk2(f[2], f[3]),
                         pk2(f[4], f[5]), pk2(f[6], f[7]));
    *(uint4*)&Al[ci * 8] = u;
  }
#pragma unroll
  for (int it = 0; it < 2; it++) {
    int mt = tid + it * 256;
    int col4 = mt % 32, ko = mt / 32;
    float fb[8][4];
#pragma unroll
    for (int i2 = 0; i2 < 8; i2++)
      *(float4*)&fb[i2][0] = *(const float4*)&W[(size_t)(ko * 8 + i2) * 128 + col4 * 4];
    int kst = ko >> 2, kq = ko & 3;
#pragma unroll
    for (int c2 = 0; c2 < 4; c2++) {
      int col = col4 * 4 + c2;
      int ct = col >> 4, colin = col & 15;
      int ci = ((kst * 4 + kq) * NT16 + (ct ^ kq)) * 16 + colin;
      uint4 u = make_uint4(pk2(fb[0][c2], fb[1][c2]), pk2(fb[2][c2], fb[3][c2]),
                           pk2(fb[4][c2], fb[5][c2]), pk2(fb[6][c2], fb[7][c2]));
      *(uint4*)&Wl[ci * 8] = u;
    }
  }
  __syncthreads();

  f32x4 acc[NT16];
#pragma unroll
  for (int ct = 0; ct < NT16; ct++) acc[ct] = (f32x4)(0.f);
#pragma unroll
  for (int kst = 0; kst < 4; kst++) {
    bf16x8 af = *(bf16x8*)&Al[(((kst * 4 + kq_l) * 4 + (w ^ kq_l)) * 16 + rr_l) * 8];
#pragma unroll
    for (int ct = 0; ct < NT16; ct++) {
      bf16x8 bf = *(bf16x8*)&Wl[(((kst * 4 + kq_l) * NT16 + (ct ^ kq_l)) * 16 + rr_l) * 8];
      acc[ct] = __builtin_amdgcn_mfma_f32_16x16x32_bf16(af, bf, acc[ct], 0, 0, 0);
    }
  }
#pragma unroll
  for (int rg = 0; rg < 4; rg++) {
    int row = row0 + w * 16 + (l >> 4) * 4 + rg;
    if (row < N_NODES) {
#pragma unroll
      for (int ct = 0; ct < NT16; ct++)
        C[(size_t)row * 128 + ct * 16 + (l & 15)] = f2bf(acc[ct][rg]);
    }
  }
}

// ================= role: fused agg1 + gcn2 =================
// Block owns 64 nodes: gather-agg h1 (dinv both sides, +b1, relu) -> Al (bf16,
// MFMA layout), then C[64x64] = Al @ W2, prescaled by dinv -> h2' bf16.
__device__ __forceinline__ void role_agg_gcn(char* smemc, int row0,
    const unsigned short* __restrict__ h1, const float* __restrict__ dinv,
    const int* __restrict__ row_lo, const int* __restrict__ deg,
    const int* __restrict__ csr_src, const float* __restrict__ b1,
    const float* __restrict__ W2, unsigned short* __restrict__ out) {
  short* Al = (short*)smemc;            // 16 KB
  short* Wl = (short*)(smemc + 16384);  // 16 KB
  const int tid = threadIdx.x;
  // ---- stage W2 (fp32 128x64 -> bf16 MFMA layout, NT16=4) ----
  {
    int col4 = tid & 15, ko = tid >> 4;
    float fb[8][4];
#pragma unroll
    for (int i2 = 0; i2 < 8; i2++)
      *(float4*)&fb[i2][0] = *(const float4*)&W2[(size_t)(ko * 8 + i2) * 64 + col4 * 4];
    int kst = ko >> 2, kq = ko & 3;
#pragma unroll
    for (int c2 = 0; c2 < 4; c2++) {
      int col = col4 * 4 + c2;
      int ct = col >> 4, colin = col & 15;
      int ci = ((kst * 4 + kq) * 4 + (ct ^ kq)) * 16 + colin;
      uint4 u = make_uint4(pk2(fb[0][c2], fb[1][c2]), pk2(fb[2][c2], fb[3][c2]),
                           pk2(fb[4][c2], fb[5][c2]), pk2(fb[6][c2], fb[7][c2]));
      *(uint4*)&Wl[ci * 8] = u;
    }
  }
  // ---- gather phase: 4 rounds x 16 nodes; lane owns feats [lane*8, lane*8+8) ----
  const int grp = tid >> 4, lane = tid & 15;
  const uint* hu = (const uint*)h1;   // 64 uints per h1 row
  float bb[8];
  *(float4*)&bb[0] = *(const float4*)&b1[lane * 8];
  *(float4*)&bb[4] = *(const float4*)&b1[lane * 8 + 4];
#pragma unroll 1
  for (int rnd = 0; rnd < 4; rnd++) {
    int r = rnd * 16 + grp;
    int n = row0 + r;
    float f[8] = {0.f, 0.f, 0.f, 0.f, 0.f, 0.f, 0.f, 0.f};
    if (n < N_NODES) {
      float dn = dinv[n];
      float acc[8];
      uint r0[4];
      *(uint4*)r0 = *(const uint4*)&hu[(size_t)n * 64 + lane * 4];
#pragma unroll
      for (int j = 0; j < 4; j++) { acc[2*j] = dn * bflo(r0[j]); acc[2*j+1] = dn * bfhi(r0[j]); }
      int lo = row_lo[n], hiEnd = lo + deg[n];
      int i = lo;
      for (; i + 8 <= hiEnd; i += 8) {
        int ss[8];
#pragma unroll
        for (int u = 0; u < 8; u++) ss[u] = csr_src[i + u];
        uint a[8][4];
#pragma unroll
        for (int u = 0; u < 8; u++)
          *(uint4*)a[u] = *(const uint4*)&hu[(size_t)ss[u] * 64 + lane * 4];
        float wv[8];
#pragma unroll
        for (int u = 0; u < 8; u++) wv[u] = dinv[ss[u]];
#pragma unroll
        for (int u = 0; u < 8; u++)
#pragma unroll
          for (int j = 0; j < 4; j++) {
            acc[2*j]   = fmaf(wv[u], bflo(a[u][j]), acc[2*j]);
            acc[2*j+1] = fmaf(wv[u], bfhi(a[u][j]), acc[2*j+1]);
          }
      }
      for (; i < hiEnd; i++) {
        int s0 = csr_src[i];
        uint a0[4];
        *(uint4*)a0 = *(const uint4*)&hu[(size_t)s0 * 64 + lane * 4];
        float w0 = dinv[s0];
#pragma unroll
        for (int j = 0; j < 4; j++) {
          acc[2*j]   = fmaf(w0, bflo(a0[j]), acc[2*j]);
          acc[2*j+1] = fmaf(w0, bfhi(a0[j]), acc[2*j+1]);
        }
      }
#pragma unroll
      for (int j = 0; j < 8; j++) f[j] = fmaxf(fmaf(dn, acc[j], bb[j]), 0.f);
    }
    int kst = lane >> 2, kq = lane & 3;
    int ci = ((kst * 4 + kq) * 4 + (rnd ^ kq)) * 16 + grp;
    uint4 u = make_uint4(pk2(f[0], f[1]), pk2(f[2], f[3]),
                         pk2(f[4], f[5]), pk2(f[6], f[7]));
    *(uint4*)&Al[ci * 8] = u;
  }
  __syncthreads();
  // ---- MFMA: C = Al @ Wl, scale dinv, bf16 out ----
  const int l = tid & 63, w = tid >> 6;
  const int kq_l = l >> 4, rr_l = l & 15;
  f32x4 acc2[4];
#pragma unroll
  for (int ct = 0; ct < 4; ct++) acc2[ct] = (f32x4)(0.f);
#pragma unroll
  for (int kst = 0; kst < 4; kst++) {
    bf16x8 af = *(bf16x8*)&Al[(((kst * 4 + kq_l) * 4 + (w ^ kq_l)) * 16 + rr_l) * 8];
#pragma unroll
    for (int ct = 0; ct < 4; ct++) {
      bf16x8 bf = *(bf16x8*)&Wl[(((kst * 4 + kq_l) * 4 + (ct ^ kq_l)) * 16 + rr_l) * 8];
      acc2[ct] = __builtin_amdgcn_mfma_f32_16x16x32_bf16(af, bf, acc2[ct], 0, 0, 0);
    }
  }
#pragma unroll
  for (int rg = 0; rg < 4; rg++) {
    int orow = row0 + w * 16 + (l >> 4) * 4 + rg;
    if (orow < N_NODES) {
      float dsc = dinv[orow];
#pragma unroll
      for (int ct = 0; ct < 4; ct++)
        out[(size_t)orow * 64 + ct * 16 + (l & 15)] = f2bf(acc2[ct][rg] * dsc);
    }
  }
}

// ================= fused kernels =================
__global__ __launch_bounds__(256)
void k_front(const float* __restrict__ img, const float* __restrict__ Wm0,
             float* __restrict__ partial,
             const float* __restrict__ x, const float* __restrict__ W1,
             unsigned short* __restrict__ bufA,
             const int* __restrict__ src, const int* __restrict__ dst,
             uint* __restrict__ ebuf, int* __restrict__ cnt) {
  __shared__ __align__(16) char smem[49152];
  int b = blockIdx.x;
  if (b < NB_IMG) {
    role_img(smem, b, img, Wm0, partial);
  } else if (b < NB_IMG + NB_GCN1) {
    role_gcn1(smem, (b - NB_IMG) * 64, x, W1, bufA);
  } else {
    role_bucket(smem, b - NB_IMG - NB_GCN1, src, dst, ebuf, cnt);
  }
}

__global__ __launch_bounds__(256)
void k_mid(const uint* __restrict__ ebuf, const int* __restrict__ cnt,
           int* __restrict__ deg, int* __restrict__ row_lo,
           float* __restrict__ dinv, int* __restrict__ csr,
           const float* __restrict__ partial, const float* __restrict__ bm0,
           float* __restrict__ tmp1, float* __restrict__ gacc) {
  __shared__ __align__(16) char smem[45056];
  int b = blockIdx.x;
  if (b < NBUCK) {
    role_binfill(smem, b, ebuf, cnt, deg, row_lo, dinv, csr);
  } else if (b < NBUCK + 256) {
    int i = (b - NBUCK) * 256 + threadIdx.x;
    float s = bm0[i & 1023];
    for (int ks = 0; ks < KSPLIT; ks++) s += partial[(size_t)ks * 65536 + i];
    tmp1[i] = s;
  } else {
    for (int j = threadIdx.x; j < NGR * 64; j += 256) gacc[j] = 0.f;
  }
}

__global__ __launch_bounds__(256)
void k_fuse3(const unsigned short* __restrict__ h1, const float* __restrict__ dinv,
             const int* __restrict__ row_lo, const int* __restrict__ deg,
             const int* __restrict__ csr, const float* __restrict__ b1,
             const float* __restrict__ W2, unsigned short* __restrict__ h2,
             const float* __restrict__ T, const float* __restrict__ Wm1,
             const float* __restrict__ bm1, float* __restrict__ x0) {
  __shared__ __align__(16) char smem[32768];
  __shared__ float red[4][64];
  int b = blockIdx.x;
  if (b < 64) {  // img_gemm2: x0 = T @ Wm1 + bm1
    int r = b;
    int c = threadIdx.x & 63;
    int q = threadIdx.x >> 6;
    float acc = 0.f;
#pragma unroll 8
    for (int k = q; k < 1024; k += 4)
      acc = fmaf(T[r * 1024 + k], Wm1[k * 64 + c], acc);
    red[q][c] = acc;
    __syncthreads();
    if (q == 0) x0[r * 64 + c] = red[0][c] + red[1][c] + red[2][c] + red[3][c] + bm1[c];
  } else {
    role_agg_gcn(smem, (b - 64) * 64, h1, dinv, row_lo, deg, csr, b1, W2, h2);
  }
}

// agg2 fused with global_add_pool: gather h2' rows, relu(dinv*acc + b2),
// per-graph LDS reduce (batch sorted), atomicAdd into gacc[64][64].
__global__ __launch_bounds__(256)
void k_aggpool(const unsigned short* __restrict__ h2, const float* __restrict__ dinv,
               const int* __restrict__ row_lo, const int* __restrict__ deg,
               const int* __restrict__ csr_src, const float* __restrict__ b2,
               const int* __restrict__ batch, float* __restrict__ gacc) {
  __shared__ float sacc[16][64];
  __shared__ int sgid[16];
  const int tid = threadIdx.x;
  const int grp = tid >> 4, lane = tid & 15;
  int n = blockIdx.x * 16 + grp;   // grid = 6250 -> n < 100000 always
  const uint* hu = (const uint*)h2;  // 32 uints per row
  float dn = dinv[n];
  float acc[4];
  uint r0[2];
  *(uint2*)r0 = *(const uint2*)&hu[(size_t)n * 32 + lane * 2];
  acc[0] = bflo(r0[0]); acc[1] = bfhi(r0[0]); acc[2] = bflo(r0[1]); acc[3] = bfhi(r0[1]);
  int lo = row_lo[n], hiEnd = lo + deg[n];
  int i = lo;
  for (; i + 8 <= hiEnd; i += 8) {
    int ss[8];
#pragma unroll
    for (int u = 0; u < 8; u++) ss[u] = csr_src[i + u];
    uint a[8][2];
#pragma unroll
    for (int u = 0; u < 8; u++)
      *(uint2*)a[u] = *(const uint2*)&hu[(size_t)ss[u] * 32 + lane * 2];
#pragma unroll
    for (int u = 0; u < 8; u++) {
      acc[0] += bflo(a[u][0]); acc[1] += bfhi(a[u][0]);
      acc[2] += bflo(a[u][1]); acc[3] += bfhi(a[u][1]);
    }
  }
  for (; i < hiEnd; i++) {
    uint a0[2];
    *(uint2*)a0 = *(const uint2*)&hu[(size_t)csr_src[i] * 32 + lane * 2];
    acc[0] += bflo(a0[0]); acc[1] += bfhi(a0[0]);
    acc[2] += bflo(a0[1]); acc[3] += bfhi(a0[1]);
  }
  float bb[4];
  *(float4*)bb = *(const float4*)&b2[lane * 4];
#pragma unroll
  for (int j = 0; j < 4; j++) acc[j] = fmaxf(fmaf(dn, acc[j], bb[j]), 0.f);
  *(float4*)&sacc[grp][lane * 4] = *(float4*)acc;
  if (lane == 0) sgid[grp] = batch[n];
  __syncthreads();
  if (tid < 64) {
    int f = tid;
    int cur = sgid[0];
    float s = 0.f;
#pragma unroll
    for (int g2 = 0; g2 < 16; g2++) {
      int gg = sgid[g2];
      if (gg != cur) { atomicAdd(&gacc[cur * 64 + f], s); cur = gg; s = 0.f; }
      s += sacc[g2][f];
    }
    atomicAdd(&gacc[cur * 64 + f], s);
  }
}

// head only: g = gacc (fp32), then Wmx, concat x0, Wfc, log_softmax
__global__ __launch_bounds__(64)
void k_head(const float* __restrict__ gacc, const float* __restrict__ x0,
            const float* __restrict__ Wmx, const float* __restrict__ bmx,
            const float* __restrict__ Wfc, const float* __restrict__ bfc,
            float* __restrict__ out) {
  int r = blockIdx.x;
  int c = threadIdx.x;
  __shared__ float sx[128];
  __shared__ float slog[NCLS];
  __shared__ float sred;
  float a2 = bmx[c];
#pragma unroll 8
  for (int k = 0; k < 64; k++) a2 = fmaf(gacc[r * 64 + k], Wmx[k * 64 + c], a2);
  sx[64 + c] = a2;
  sx[c] = x0[r * 64 + c];
  __syncthreads();
  float lg = 0.f;
  if (c < NCLS) {
    lg = bfc[c];
#pragma unroll 8
    for (int k = 0; k < 128; k++) lg = fmaf(sx[k], Wfc[k * NCLS + c], lg);
    slog[c] = lg;
  }
  __syncthreads();
  if (c == 0) {
    float m = -1e30f;
    for (int j = 0; j < NCLS; j++) m = fmaxf(m, slog[j]);
    float s = 0.f;
    for (int j = 0; j < NCLS; j++) s += expf(slog[j] - m);
    sred = m + logf(s);
  }
  __syncthreads();
  if (c < NCLS) out[r * NCLS + c] = lg - sred;
}

// ---------------- launch ----------------
extern "C" void kernel_launch(void* const* d_in, const int* in_sizes, int n_in,
                              void* d_out, int out_size, void* d_ws, size_t ws_size,
                              hipStream_t stream) {
  const float* x    = (const float*)d_in[0];
  const int*   edge = (const int*)d_in[1];
  const float* img  = (const float*)d_in[2];
  const int*   batch= (const int*)d_in[3];
  const float* W1   = (const float*)d_in[4];
  const float* b1   = (const float*)d_in[5];
  const float* W2   = (const float*)d_in[6];
  const float* b2   = (const float*)d_in[7];
  const float* Wm0  = (const float*)d_in[8];
  const float* bm0  = (const float*)d_in[9];
  const float* Wm1  = (const float*)d_in[10];
  const float* bm1  = (const float*)d_in[11];
  const float* Wmx  = (const float*)d_in[12];
  const float* bmx  = (const float*)d_in[13];
  const float* Wfc  = (const float*)d_in[14];
  const float* bfc  = (const float*)d_in[15];
  float* out = (float*)d_out;
  const int* srcp = edge;
  const int* dstp = edge + N_EDGES;

  char* ws = (char*)d_ws;
  size_t off = 0;
  auto alloc = [&](size_t bytes) {
    void* p = ws + off;
    off += (bytes + 255) & ~(size_t)255;
    return p;
  };
  int*   cnt    = (int*)  alloc((size_t)NBUCK * NB_BUCK * 4);
  uint*  ebuf   = (uint*) alloc((size_t)NBUCK * NB_BUCK * CELLCAP * 4);
  int*   csr    = (int*)  alloc((size_t)NBUCK * BCAP * 4);
  int*   deg    = (int*)  alloc((size_t)N_NODES * 4);
  int*   row_lo = (int*)  alloc((size_t)N_NODES * 4);
  float* dinv   = (float*)alloc((size_t)N_NODES * 4);
  unsigned short* bufA = (unsigned short*)alloc((size_t)N_NODES * 128 * 2);
  unsigned short* bufB = (unsigned short*)alloc((size_t)N_NODES * 128 * 2);  // >= partial 12.85 MB
  float* tmp1   = (float*)alloc(64 * 1024 * 4);
  float* x0     = (float*)alloc(64 * 64 * 4);
  float* gacc   = (float*)alloc((size_t)NGR * 64 * 4);
  float* partial = (float*)bufB;  // consumed by k_mid before k_fuse3 overwrites bufB
  (void)ws_size; (void)in_sizes; (void)n_in; (void)out_size;

  // K1: img GEMM || gcn layer-1 GEMM (unscaled) || edge bucketing
  k_front<<<NB_FRONT, 256, 0, stream>>>(
      img, Wm0, partial, x, W1, bufA, srcp, dstp, ebuf, cnt);
  // K2: per-bucket CSR fill || img split-K reduce || zero gacc
  k_mid<<<NBUCK + 256 + 1, 256, 0, stream>>>(
      ebuf, cnt, deg, row_lo, dinv, csr, partial, bm0, tmp1, gacc);
  // K3: img gemm2 || fused agg1+gcn2 -> h2' (bufB)
  k_fuse3<<<64 + NB_GCN1, 256, 0, stream>>>(
      bufA, dinv, row_lo, deg, csr, b1, W2, bufB, tmp1, Wm1, bm1, x0);
  // K4: fused agg2 + global_add_pool -> gacc
  k_aggpool<<<NB_AGGP, 256, 0, stream>>>(
      bufB, dinv, row_lo, deg, csr, b2, batch, gacc);
  // K5: head
  k_head<<<NGR, 64, 0, stream>>>(gacc, x0, Wmx, bmx, Wfc, bfc, out);
}